// Round 7
// baseline (153.577 us; speedup 1.0000x reference)
//
#include <hip/hip_runtime.h>
#include <hip/hip_bf16.h>
#include <math.h>

#define NNODES 100000
#define FIN 500
#define KPAD 512
#define HIDDIM 64
#define NCLS 40
#define KORD 10

typedef __bf16 bf16x4 __attribute__((ext_vector_type(4)));
typedef __bf16 bf16x8 __attribute__((ext_vector_type(8)));
typedef float f32x4 __attribute__((ext_vector_type(4)));

// ---------------- polynomial coefficients + need-flags from temp ----------------
// out = sum_j C(K,j)/2^K * relu(temp[j]) * (I-A)^j (I+A)^{K-j} h = sum_m g[m] A^m h
// g[m] = sum_j s_j * T[j][m], T[j][m] = coeff of x^m in (1-x)^j (1+x)^{K-j}.
// All intermediates are integers/1024 with numerators < 2^24, exact in f32.
// flags[m] = 1 iff any g[j] != 0 for j >= m  (SpMV step m still needed).
__global__ void coeff_kernel(const float* __restrict__ temp, float* __restrict__ g,
                             int* __restrict__ flags) {
  if (threadIdx.x != 0 || blockIdx.x != 0) return;
  float C[KORD + 1][KORD + 1];
  for (int n = 0; n <= KORD; ++n)
    for (int k = 0; k <= KORD; ++k) C[n][k] = 0.f;
  for (int n = 0; n <= KORD; ++n) {
    C[n][0] = 1.f;
    for (int k = 1; k <= n; ++k) C[n][k] = C[n - 1][k - 1] + C[n - 1][k];
  }
  float s[KORD + 1];
  for (int j = 0; j <= KORD; ++j) {
    float th = temp[j] > 0.f ? temp[j] : 0.f;
    s[j] = C[KORD][j] * (1.0f / 1024.0f) * th;
  }
  for (int m = 0; m <= KORD; ++m) {
    float acc = 0.f;
    for (int j = 0; j <= KORD; ++j) {
      float T = 0.f;
      for (int a = 0; a <= m; ++a) {
        int b = m - a;
        if (a <= j && b <= KORD - j)
          T += ((a & 1) ? -1.f : 1.f) * C[j][a] * C[KORD - j][b];
      }
      acc += s[j] * T;
    }
    g[m] = acc;
  }
  int any = 0;
  flags[0] = 1;
  for (int m = KORD; m >= 1; --m) {
    if (g[m] != 0.f) any = 1;
    flags[m] = any;
  }
}

// ---------------- gated zero of CSR-build scratch ----------------
__global__ __launch_bounds__(256) void zero_kernel(int* __restrict__ p,
                                                   const int* __restrict__ flags,
                                                   int nwords) {
  if (flags[1] == 0) return;
  for (int i = blockIdx.x * 256 + threadIdx.x; i < nwords; i += gridDim.x * 256)
    p[i] = 0;
}

// ---------------- counts: out-degree at src + in-degree at dst ----------------
__global__ __launch_bounds__(256) void cnt_kernel(const int* __restrict__ src,
                                                  const int* __restrict__ dst,
                                                  int* __restrict__ deg_i,
                                                  int* __restrict__ cnt_dst,
                                                  const int* __restrict__ flags, int E) {
  if (flags[1] == 0) return;
  for (int e = blockIdx.x * 256 + threadIdx.x; e < E; e += gridDim.x * 256) {
    atomicAdd(&deg_i[src[e]], 1);
    atomicAdd(&cnt_dst[dst[e]], 1);
  }
}

__global__ __launch_bounds__(256) void dis_kernel(const int* __restrict__ deg_i,
                                                  float* __restrict__ dis,
                                                  const int* __restrict__ flags, int n) {
  if (flags[1] == 0) return;
  for (int i = blockIdx.x * 256 + threadIdx.x; i < n; i += gridDim.x * 256) {
    int d = deg_i[i];
    dis[i] = d > 0 ? 1.0f / sqrtf((float)d) : 0.f;
  }
}

// ---------------- exclusive prefix sum of cnt_dst -> rowptr[0..n] ----------------
__global__ __launch_bounds__(1024) void scan_kernel(const int* __restrict__ cnt,
                                                    int* __restrict__ rowptr,
                                                    const int* __restrict__ flags) {
  if (flags[1] == 0) return;
  __shared__ int part[1024];
  int t = threadIdx.x;
  const int chunk = (NNODES + 1023) / 1024;
  int lo = t * chunk, hi = lo + chunk;
  if (hi > NNODES) hi = NNODES;
  int s = 0;
  for (int i = lo; i < hi; ++i) s += cnt[i];
  part[t] = s;
  __syncthreads();
  for (int off = 1; off < 1024; off <<= 1) {
    int v = (t >= off) ? part[t - off] : 0;
    __syncthreads();
    part[t] += v;
    __syncthreads();
  }
  int run = (t > 0) ? part[t - 1] : 0;
  for (int i = lo; i < hi; ++i) {
    rowptr[i] = run;
    run += cnt[i];
  }
  if (t == 1023) rowptr[NNODES] = run;
}

// ---------------- CSR fill (dst-major): col[pos] = src ----------------
__global__ __launch_bounds__(256) void fill_kernel(const int* __restrict__ src,
                                                   const int* __restrict__ dst,
                                                   const int* __restrict__ rowptr,
                                                   int* __restrict__ tmpc,
                                                   int* __restrict__ col,
                                                   const int* __restrict__ flags, int E) {
  if (flags[1] == 0) return;
  for (int e = blockIdx.x * 256 + threadIdx.x; e < E; e += gridDim.x * 256) {
    int d = dst[e];
    int pos = rowptr[d] + atomicAdd(&tmpc[d], 1);
    col[pos] = src[e];
  }
}

// ---------------- W1 -> transposed bf16, K padded to 512: w1t[c][k] ----------------
__global__ __launch_bounds__(256) void w1t_kernel(const float* __restrict__ W1,
                                                  __bf16* __restrict__ w1t) {
  int idx = blockIdx.x * 256 + threadIdx.x;
  if (idx >= HIDDIM * KPAD) return;
  int c = idx >> 9, k = idx & (KPAD - 1);
  float v = (k < FIN) ? W1[(size_t)k * HIDDIM + c] : 0.f;
  w1t[(size_t)c * KPAD + k] = (__bf16)v;
}

// ---------------- fused MLP: u = relu(x@W1+b1)@W2+b2 ; out = g0*u ----------------
// GEMM1: bf16 MFMA 16x16x32, K chunked by 64, double-buffered bf16 LDS tiles
// (reg-staged: f32 global -> cvt -> ds_write_b64), one barrier per chunk.
// LDS A-tile layout: row r at byte r*128; 16B unit u holds k = (u^(r&7))*8..+7
// (XOR swizzle -> fragment reads are <=2-way bank conflicts, free).
// arena map: [0,8K) buf0 | [8K,16K) buf1 | post-loop hs [8K,24.25K) | w2s [24.25K,34.25K)
__global__ __launch_bounds__(256, 4) void mlp_kernel(
    const float* __restrict__ x, const __bf16* __restrict__ w1t,
    const float* __restrict__ b1, const float* __restrict__ W2,
    const float* __restrict__ b2, const float* __restrict__ g,
    float* __restrict__ u, float* __restrict__ out, int n) {
  __shared__ __align__(16) char arena[35072];
  const int t = threadIdx.x;
  const int w = t >> 6, lane = t & 63;
  const int row0 = blockIdx.x * 64;

  float* w2s = (float*)(arena + 24832);
  for (int i = t; i < HIDDIM * NCLS; i += 256) w2s[i] = W2[i];

  const int bcol = w * 16 + (lane & 15);  // this lane's B column (= output col)
  const int koff = (lane >> 4) * 8;       // k offset within a 32-k MFMA tile
  const __bf16* wrow = w1t + (size_t)bcol * KPAD + koff;

  // staging coords: thread covers (row, 4-f32 group) pairs, 4 per chunk
  int srow[4], spos[4];
#pragma unroll
  for (int i = 0; i < 4; ++i) {
    int lin = i * 256 + t;
    srow[i] = lin >> 4;
    spos[i] = lin & 15;
  }

  f32x4 acc[4] = {};
  bf16x8 bcur[2];

  // ---- prologue: stage chunk 0, load B(0) ----
  {
    float4 q[4];
#pragma unroll
    for (int i = 0; i < 4; ++i) {
      int gr = row0 + srow[i], k0 = spos[i] * 4;
      q[i] = (gr < NNODES && k0 < FIN)
                 ? *(const float4*)(x + (size_t)gr * FIN + k0)
                 : make_float4(0.f, 0.f, 0.f, 0.f);
    }
#pragma unroll
    for (int i = 0; i < 4; ++i) {
      int r = srow[i], pos = spos[i];
      bf16x4 h;
      h[0] = (__bf16)q[i].x; h[1] = (__bf16)q[i].y;
      h[2] = (__bf16)q[i].z; h[3] = (__bf16)q[i].w;
      *(bf16x4*)(arena + r * 128 + (((pos >> 1) ^ (r & 7)) << 4) + ((pos & 1) << 3)) = h;
    }
    bcur[0] = *(const bf16x8*)(wrow);
    bcur[1] = *(const bf16x8*)(wrow + 32);
  }
  __syncthreads();

  // ---- main loop: 8 chunks of K=64 ----
  for (int c = 0; c < 8; ++c) {
    const char* buf = arena + ((c & 1) << 13);
    float4 qn[4];
    bf16x8 bnxt[2];
    if (c < 7) {
      int kc = (c + 1) * 64;
#pragma unroll
      for (int i = 0; i < 4; ++i) {
        int gr = row0 + srow[i], k0 = kc + spos[i] * 4;
        qn[i] = (gr < NNODES && k0 < FIN)
                    ? *(const float4*)(x + (size_t)gr * FIN + k0)
                    : make_float4(0.f, 0.f, 0.f, 0.f);
      }
      bnxt[0] = *(const bf16x8*)(wrow + kc);
      bnxt[1] = *(const bf16x8*)(wrow + kc + 32);
    }
#pragma unroll
    for (int kt = 0; kt < 2; ++kt) {
      int uu = kt * 4 + (lane >> 4);
#pragma unroll
      for (int rt = 0; rt < 4; ++rt) {
        int r = rt * 16 + (lane & 15);
        bf16x8 a = *(const bf16x8*)(buf + r * 128 + ((uu ^ (r & 7)) << 4));
        acc[rt] = __builtin_amdgcn_mfma_f32_16x16x32_bf16(a, bcur[kt], acc[rt], 0, 0, 0);
      }
    }
    if (c < 7) {
      char* nbuf = arena + (((c + 1) & 1) << 13);
#pragma unroll
      for (int i = 0; i < 4; ++i) {
        int r = srow[i], pos = spos[i];
        bf16x4 h;
        h[0] = (__bf16)qn[i].x; h[1] = (__bf16)qn[i].y;
        h[2] = (__bf16)qn[i].z; h[3] = (__bf16)qn[i].w;
        *(bf16x4*)(nbuf + r * 128 + (((pos >> 1) ^ (r & 7)) << 4) + ((pos & 1) << 3)) = h;
      }
      bcur[0] = bnxt[0];
      bcur[1] = bnxt[1];
    }
    __syncthreads();
  }

  // ---- epilogue: hs = relu(acc + b1) -> LDS; GEMM2 f32; fused out = g0*u ----
  float* hs = (float*)(arena + 8192);  // [64][65]
  {
    float bv = b1[bcol];
#pragma unroll
    for (int rt = 0; rt < 4; ++rt)
#pragma unroll
      for (int reg = 0; reg < 4; ++reg) {
        int rrow = rt * 16 + (lane >> 4) * 4 + reg;
        float v = acc[rt][reg] + bv;
        hs[rrow * 65 + bcol] = v > 0.f ? v : 0.f;
      }
  }
  __syncthreads();

  int row = t >> 2, cg = (t & 3) * 10;
  float o[10] = {};
  for (int k = 0; k < HIDDIM; ++k) {
    float a = hs[row * 65 + k];
#pragma unroll
    for (int j = 0; j < 10; ++j) o[j] += a * w2s[k * 40 + cg + j];
  }
  int gr = row0 + row;
  if (gr < n) {
    float g0 = g[0];
    float* urow = u + (size_t)gr * NCLS + cg;
    float* orow = out + (size_t)gr * NCLS + cg;
#pragma unroll
    for (int j = 0; j < 10; ++j) {
      float val = o[j] + b2[cg + j];
      urow[j] = val;
      orow[j] = g0 * val;
    }
  }
}

// ---------------- SpMV step m: uout = D^-1/2 A D^-1/2 uin ; out += g[m]*uout ----------------
// Wave per node (grid-stride); lanes 0..39 own feature columns. Matches reference
// associativity: sum over edges of (dis[src]*uin[src]), then * dis[dst].
__global__ __launch_bounds__(256) void spmv_kernel(
    const int* __restrict__ col, const int* __restrict__ rowptr,
    const float* __restrict__ dis, const float* __restrict__ uin,
    float* __restrict__ uout, float* __restrict__ out, const float* __restrict__ g,
    const int* __restrict__ flags, int m) {
  if (flags[m] == 0) return;
  int lane = threadIdx.x & 63;
  if (lane >= NCLS) return;
  int stride = gridDim.x * 4;
  for (int wid = blockIdx.x * 4 + (threadIdx.x >> 6); wid < NNODES; wid += stride) {
    int lo = rowptr[wid], hi = rowptr[wid + 1];
    float acc = 0.f;
    for (int e = lo; e < hi; ++e) {
      int s = col[e];
      acc += dis[s] * uin[(size_t)s * NCLS + lane];
    }
    acc *= dis[wid];
    size_t idx = (size_t)wid * NCLS + lane;
    uout[idx] = acc;
    out[idx] += g[m] * acc;
  }
}

// ---------------- log_softmax: one 64-lane wave per row (grid-stride) ----------------
__global__ __launch_bounds__(256) void lsm_kernel(const float* __restrict__ out,
                                                  float* __restrict__ lsm, int n) {
  int lane = threadIdx.x & 63;
  int stride = gridDim.x * 4;
  for (int wid = blockIdx.x * 4 + (threadIdx.x >> 6); wid < n; wid += stride) {
    float xv = (lane < NCLS) ? out[(size_t)wid * NCLS + lane] : -INFINITY;
    float mx = xv;
#pragma unroll
    for (int off = 32; off; off >>= 1) mx = fmaxf(mx, __shfl_xor(mx, off));
    float e = (lane < NCLS) ? expf(xv - mx) : 0.f;
    float sum = e;
#pragma unroll
    for (int off = 32; off; off >>= 1) sum += __shfl_xor(sum, off);
    float lse = logf(sum);
    if (lane < NCLS) lsm[(size_t)wid * NCLS + lane] = xv - mx - lse;
  }
}

extern "C" void kernel_launch(void* const* d_in, const int* in_sizes, int n_in,
                              void* d_out, int out_size, void* d_ws, size_t ws_size,
                              hipStream_t stream) {
  (void)n_in; (void)out_size; (void)ws_size;
  const float* x = (const float*)d_in[0];
  const int* ei = (const int*)d_in[1];
  const float* W1 = (const float*)d_in[2];
  const float* b1 = (const float*)d_in[3];
  const float* W2 = (const float*)d_in[4];
  const float* b2 = (const float*)d_in[5];
  const float* temp = (const float*)d_in[6];
  int E = in_sizes[1] / 2;
  const int* src = ei;
  const int* dst = ei + E;
  int n = NNODES;

  // ws layout in 4-byte words; total ~7.72M words (~30.9 MB)
  float* ws = (float*)d_ws;
  float* ua = ws;                          // 4,000,000 f32
  int* col = (int*)(ws + 4000000);         // 3,200,000 i32
  int* cnt_dst = (int*)(ws + 7200000);     // 100,000 i32 (zero_kernel covers this + next two)
  int* tmpc = (int*)(ws + 7300000);        // 100,000 i32
  int* deg_i = (int*)(ws + 7400000);       // 100,000 i32
  int* rowptr = (int*)(ws + 7500000);      // 100,001 i32
  float* dis = ws + 7600016;               // 100,000 f32
  float* g = ws + 7700016;                 // 16 f32
  int* flags = (int*)(ws + 7700032);       // 16 i32
  __bf16* w1t = (__bf16*)(ws + 7700048);   // 32,768 bf16 = 16,384 words

  float* lsm = (float*)d_out;            // n*40, also ping-pong scratch during prop
  float* out = (float*)d_out + 4000000;  // n*40 accumulator, final output 1

  coeff_kernel<<<1, 64, 0, stream>>>(temp, g, flags);
  zero_kernel<<<64, 256, 0, stream>>>(cnt_dst, flags, 300000);
  cnt_kernel<<<128, 256, 0, stream>>>(src, dst, deg_i, cnt_dst, flags, E);
  dis_kernel<<<64, 256, 0, stream>>>(deg_i, dis, flags, n);
  scan_kernel<<<1, 1024, 0, stream>>>(cnt_dst, rowptr, flags);
  fill_kernel<<<128, 256, 0, stream>>>(src, dst, rowptr, tmpc, col, flags, E);
  w1t_kernel<<<(HIDDIM * KPAD + 255) / 256, 256, 0, stream>>>(W1, w1t);
  mlp_kernel<<<(n + 63) / 64, 256, 0, stream>>>(x, w1t, b1, W2, b2, g, ua, out, n);
  for (int m = 1; m <= KORD; ++m) {
    float* uin = (m & 1) ? ua : lsm;
    float* uout = (m & 1) ? lsm : ua;
    spmv_kernel<<<256, 256, 0, stream>>>(col, rowptr, dis, uin, uout, out, g, flags, m);
  }
  lsm_kernel<<<1024, 256, 0, stream>>>(out, lsm, n);
}